// Round 1
// baseline (152.966 us; speedup 1.0000x reference)
//
#include <hip/hip_runtime.h>
#include <math.h>

#define N_S  1024   // number of samples
#define XD   768    // x / y feature dim
#define LOW  300    // LOWER
#define KP   304    // LOWER padded to multiple of 16

// ---------------------------------------------------------------------------
// Kernel 1: projections.
//   which==0 : hxT[k][j] = sum_m x[j,m] * W1[m,k]          (stored transposed)
//   which==1 : hyb[i][k] = sum_m y[i,m] * W1[768+m,k] + b1[k]
// K rows/cols in [300,304) are written as exact zeros (padding).
// ---------------------------------------------------------------------------
__global__ __launch_bounds__(256)
void gemm_h(const float* __restrict__ x, const float* __restrict__ y,
            const float* __restrict__ W1, const float* __restrict__ b1,
            float* __restrict__ hxT, float* __restrict__ hyb)
{
    const int which = blockIdx.z;               // 0: x -> hxT, 1: y -> hyb
    const float* A = which ? y : x;
    const float* W = W1 + (which ? XD * LOW : 0);

    const int r0 = blockIdx.y * 64;             // sample-row tile
    const int k0 = blockIdx.x * 64;             // output-col (k) tile

    __shared__ float As[64][17];                // [row][kk], padded
    __shared__ float Ws[16][64];                // [kk][kcol]

    const int tid = threadIdx.x;
    const int tx = tid & 15, ty = tid >> 4;

    float acc[4][4] = {};

    for (int kb = 0; kb < XD; kb += 16) {
        {   // stage A tile: 64 rows x 16 m  (64B-coalesced)
            int mm = tid & 15, r = tid >> 4;
            #pragma unroll
            for (int s = 0; s < 4; ++s)
                As[r + 16*s][mm] = A[(size_t)(r0 + r + 16*s) * XD + kb + mm];
        }
        {   // stage W tile: 16 m x 64 k (coalesced), zero past LOW
            int kc = tid & 63, mm = tid >> 6;
            #pragma unroll
            for (int s = 0; s < 4; ++s) {
                int kg = k0 + kc;
                Ws[mm + 4*s][kc] = (kg < LOW) ? W[(size_t)(kb + mm + 4*s) * LOW + kg] : 0.f;
            }
        }
        __syncthreads();
        #pragma unroll
        for (int kk = 0; kk < 16; ++kk) {
            float a[4], b[4];
            #pragma unroll
            for (int i = 0; i < 4; ++i) a[i] = As[ty*4 + i][kk];
            #pragma unroll
            for (int j = 0; j < 4; ++j) b[j] = Ws[kk][tx*4 + j];
            #pragma unroll
            for (int i = 0; i < 4; ++i)
                #pragma unroll
                for (int j = 0; j < 4; ++j)
                    acc[i][j] = fmaf(a[i], b[j], acc[i][j]);
        }
        __syncthreads();
    }

    #pragma unroll
    for (int i = 0; i < 4; ++i) {
        int r = r0 + ty*4 + i;
        #pragma unroll
        for (int j = 0; j < 4; ++j) {
            int k = k0 + tx*4 + j;
            if (k < KP) {
                if (which == 0) {
                    hxT[(size_t)k * N_S + r] = acc[i][j];        // acc==0 for k>=LOW
                } else {
                    float v = acc[i][j] + ((k < LOW) ? b1[k] : 0.f);
                    hyb[(size_t)r * KP + k] = (k < LOW) ? v : 0.f;
                }
            }
        }
    }
}

// ---------------------------------------------------------------------------
// Kernel 2: pairwise critic.
//   T1[i][j] = softplus( sum_k relu(hyb[i][k] + hxT[k][j]) * w2[k] + b2 )
// 64x64 output tile per block, 4x4 register micro-tile, K staged in LDS.
// Padding (k in [300,304)) contributes relu(0+0)*0 = 0.
// ---------------------------------------------------------------------------
__global__ __launch_bounds__(256)
void pair_kernel(const float* __restrict__ hxT, const float* __restrict__ hyb,
                 const float* __restrict__ W2, const float* __restrict__ b2,
                 float* __restrict__ T1)
{
    const int i0 = blockIdx.y * 64;
    const int j0 = blockIdx.x * 64;

    __shared__ float Hy[64][17];   // [i][kk]
    __shared__ float Hx[16][64];   // [kk][j]
    __shared__ float w2s[KP];

    const int tid = threadIdx.x;
    const int tx = tid & 15, ty = tid >> 4;

    for (int k = tid; k < KP; k += 256)
        w2s[k] = (k < LOW) ? W2[k] : 0.f;

    const float b2v = b2[0];
    float acc[4][4] = {};

    for (int kb = 0; kb < KP; kb += 16) {
        {   // stage hyb tile
            int mm = tid & 15, r = tid >> 4;
            #pragma unroll
            for (int s = 0; s < 4; ++s)
                Hy[r + 16*s][mm] = hyb[(size_t)(i0 + r + 16*s) * KP + kb + mm];
        }
        {   // stage hxT tile (rows are k, coalesced along j)
            int jc = tid & 63, mm = tid >> 6;
            #pragma unroll
            for (int s = 0; s < 4; ++s)
                Hx[mm + 4*s][jc] = hxT[(size_t)(kb + mm + 4*s) * N_S + j0 + jc];
        }
        __syncthreads();
        #pragma unroll
        for (int kk = 0; kk < 16; ++kk) {
            float wv = w2s[kb + kk];
            float a[4], b[4];
            #pragma unroll
            for (int i = 0; i < 4; ++i) a[i] = Hy[ty*4 + i][kk];
            #pragma unroll
            for (int j = 0; j < 4; ++j) b[j] = Hx[kk][tx*4 + j];
            #pragma unroll
            for (int i = 0; i < 4; ++i)
                #pragma unroll
                for (int j = 0; j < 4; ++j)
                    acc[i][j] = fmaf(fmaxf(a[i] + b[j], 0.f), wv, acc[i][j]);
        }
        __syncthreads();
    }

    #pragma unroll
    for (int i = 0; i < 4; ++i) {
        int r = i0 + ty*4 + i;
        #pragma unroll
        for (int j = 0; j < 4; ++j) {
            int c = j0 + tx*4 + j;
            float s = acc[i][j] + b2v;
            // stable softplus: log1p(exp(s))
            float sp = fmaxf(s, 0.f) + log1pf(expf(-fabsf(s)));
            T1[(size_t)r * N_S + c] = sp;
        }
    }
}

// ---------------------------------------------------------------------------
// Kernel 3: per-row logsumexp + diagonal.  contrib[i] = T1[i][i] - lse_i
// ---------------------------------------------------------------------------
__device__ inline float waveReduceMax(float v) {
    #pragma unroll
    for (int o = 32; o > 0; o >>= 1) v = fmaxf(v, __shfl_down(v, o, 64));
    return v;
}
__device__ inline float waveReduceSum(float v) {
    #pragma unroll
    for (int o = 32; o > 0; o >>= 1) v += __shfl_down(v, o, 64);
    return v;
}

__global__ __launch_bounds__(256)
void row_reduce(const float* __restrict__ T1, float* __restrict__ contrib)
{
    const int i = blockIdx.x;
    const int tid = threadIdx.x;
    const float4 v = ((const float4*)(T1 + (size_t)i * N_S))[tid];

    __shared__ float sm[4];
    __shared__ float ss[4];
    const int wid = tid >> 6, lane = tid & 63;

    float m = fmaxf(fmaxf(v.x, v.y), fmaxf(v.z, v.w));
    m = waveReduceMax(m);
    if (lane == 0) sm[wid] = m;
    __syncthreads();
    const float M = fmaxf(fmaxf(sm[0], sm[1]), fmaxf(sm[2], sm[3]));

    float s = expf(v.x - M) + expf(v.y - M) + expf(v.z - M) + expf(v.w - M);
    s = waveReduceSum(s);
    if (lane == 0) ss[wid] = s;
    __syncthreads();

    if (tid == 0) {
        float lse = M + logf(ss[0] + ss[1] + ss[2] + ss[3]);
        contrib[i] = T1[(size_t)i * N_S + i] - lse;
    }
}

// ---------------------------------------------------------------------------
// Kernel 4: final mean.
// ---------------------------------------------------------------------------
__global__ __launch_bounds__(256)
void finalize(const float* __restrict__ contrib, float* __restrict__ out)
{
    const int tid = threadIdx.x;
    float s = 0.f;
    for (int j = tid; j < N_S; j += 256) s += contrib[j];
    s = waveReduceSum(s);
    __shared__ float ss[4];
    const int wid = tid >> 6, lane = tid & 63;
    if (lane == 0) ss[wid] = s;
    __syncthreads();
    if (tid == 0)
        out[0] = (ss[0] + ss[1] + ss[2] + ss[3]) * (1.0f / N_S) - logf((float)N_S);
}

// ---------------------------------------------------------------------------
extern "C" void kernel_launch(void* const* d_in, const int* in_sizes, int n_in,
                              void* d_out, int out_size, void* d_ws, size_t ws_size,
                              hipStream_t stream)
{
    const float* x  = (const float*)d_in[0];
    const float* y  = (const float*)d_in[1];
    const float* W1 = (const float*)d_in[2];
    const float* b1 = (const float*)d_in[3];
    const float* W2 = (const float*)d_in[4];
    const float* b2 = (const float*)d_in[5];
    float* out = (float*)d_out;

    float* ws      = (float*)d_ws;
    float* hxT     = ws;                          // KP * N_S
    float* hyb     = hxT + (size_t)KP * N_S;      // N_S * KP
    float* T1      = hyb + (size_t)N_S * KP;      // N_S * N_S
    float* contrib = T1 + (size_t)N_S * N_S;      // N_S

    dim3 g1(5, 16, 2);                            // k-tiles, row-tiles, {x,y}
    gemm_h<<<g1, 256, 0, stream>>>(x, y, W1, b1, hxT, hyb);

    dim3 g2(16, 16);                              // j-tiles, i-tiles
    pair_kernel<<<g2, 256, 0, stream>>>(hxT, hyb, W2, b2, T1);

    row_reduce<<<N_S, 256, 0, stream>>>(T1, contrib);
    finalize<<<1, 256, 0, stream>>>(contrib, out);
}

// Round 2
// 67.131 us; speedup vs baseline: 2.2786x; 2.2786x over previous
//
#include <hip/hip_runtime.h>
#include <math.h>

#define N_S  1024
#define XD   768
#define LOW  300
#define KP   320     // K padded (f16 storage)
#define KP2  160     // half2 (u32) per row

typedef _Float16 h2 __attribute__((ext_vector_type(2)));
union U32H2 { unsigned int u; h2 h; };
__device__ inline h2 u2h(unsigned int v){ U32H2 t; t.u = v; return t.h; }

// ---------------------------------------------------------------------------
// Kernel 1: projections, fp32 in -> f16 out (K padded to 320 with zeros).
//   which==0 : hx_h[j][k] = sum_m x[j,m] * W1[m,k]
//   which==1 : hy_h[i][k] = sum_m y[i,m] * W1[768+m,k] + b1[k]
// Tile 64 rows x 64 kcols, 512 threads, per-thread 8 rows x 1 col.
// Inner product via v_dot2_f32_f16 on h2 pairs along m (fp32 accumulate).
// ---------------------------------------------------------------------------
__global__ __launch_bounds__(512)
void gemm_h(const float* __restrict__ x, const float* __restrict__ y,
            const float* __restrict__ W1, const float* __restrict__ b1,
            unsigned int* __restrict__ hx_h, unsigned int* __restrict__ hy_h)
{
    const int which = blockIdx.z;
    const float* A = which ? y : x;
    const float* W = W1 + (size_t)which * XD * LOW;
    unsigned int* out = which ? hy_h : hx_h;

    const int k0 = blockIdx.x * 64;
    const int r0 = blockIdx.y * 64;

    __shared__ unsigned int As[64][18];   // [row][mm2] h2 pairs, b64-aligned stride
    __shared__ unsigned int Bs[64][17];   // [kcol][mm2], odd stride -> conflict-free b32

    const int tid = threadIdx.x;
    const int tx = tid & 63;              // k col
    const int ty = tid >> 6;              // wave id -> 8-row group

    const int arow = tid >> 3, aq = tid & 7;     // A staging: row, float4 group
    const int bkc  = tid & 63, bmm = tid >> 6;   // B staging: kcol, m row
    const bool bin = (k0 + bkc) < LOW;

    const int kcol = k0 + tx;
    const bool kin = (kcol < LOW);

    float acc[8] = {0,0,0,0,0,0,0,0};

    float4 av; float bw[4];
    // prologue: chunk 0
    av = *(const float4*)&A[(size_t)(r0 + arow) * XD + aq * 4];
    #pragma unroll
    for (int s = 0; s < 4; ++s)
        bw[s] = bin ? W[(size_t)(bmm + s * 8) * LOW + k0 + bkc] : 0.f;

    const int NC = XD / 32;               // 24 chunks of 32 m
    for (int c = 0; c < NC; ++c) {
        __syncthreads();
        {   // write staged regs -> LDS (converted to f16)
            U32H2 p0, p1;
            p0.h = h2{(_Float16)av.x, (_Float16)av.y};
            p1.h = h2{(_Float16)av.z, (_Float16)av.w};
            As[arow][aq * 2]     = p0.u;
            As[arow][aq * 2 + 1] = p1.u;
            _Float16* hb = (_Float16*)&Bs[0][0];
            #pragma unroll
            for (int s = 0; s < 4; ++s)
                hb[bkc * 34 + bmm + s * 8] = (_Float16)bw[s];
        }
        __syncthreads();
        if (c + 1 < NC) {                 // issue next-chunk loads; overlap compute
            const int mb = (c + 1) * 32;
            av = *(const float4*)&A[(size_t)(r0 + arow) * XD + mb + aq * 4];
            #pragma unroll
            for (int s = 0; s < 4; ++s)
                bw[s] = bin ? W[(size_t)(mb + bmm + s * 8) * LOW + k0 + bkc] : 0.f;
        }
        #pragma unroll
        for (int mm2 = 0; mm2 < 16; ++mm2) {
            h2 b = u2h(Bs[tx][mm2]);                  // stride-17: conflict-free
            #pragma unroll
            for (int r = 0; r < 8; ++r) {
                h2 a = u2h(As[ty * 8 + r][mm2]);      // wave-uniform broadcast
                acc[r] = __builtin_amdgcn_fdot2(a, b, acc[r], false);
            }
        }
    }

    const float b1v = (which && kin) ? b1[kcol] : 0.f;
    _Float16* o16 = (_Float16*)out;
    #pragma unroll
    for (int r = 0; r < 8; ++r) {
        float v = acc[r] + b1v;
        o16[(size_t)(r0 + ty * 8 + r) * KP + kcol] = kin ? (_Float16)v : (_Float16)0.f;
    }
}

// ---------------------------------------------------------------------------
// Kernel 2: pairwise critic, f16 packed math.
//   T1[i][j] = softplus( sum_k relu(hy[i,k] + hx[j,k]) * w2[k] + b2 )
// Tile 64(i) x 64(j), 512 threads, per-thread 8 rows x 1 col.
// Core: v_pk_add_f16 + v_pk_max_f16 + v_dot2_f32_f16 (3 instr / 2 k).
// ---------------------------------------------------------------------------
__global__ __launch_bounds__(512)
void pair_kernel(const unsigned int* __restrict__ hx_h, const unsigned int* __restrict__ hy_h,
                 const float* __restrict__ W2, const float* __restrict__ b2,
                 float* __restrict__ T1)
{
    const int j0 = blockIdx.x * 64;
    const int i0 = blockIdx.y * 64;

    __shared__ unsigned int Hy[64][17];
    __shared__ unsigned int Hx[64][17];
    __shared__ unsigned int w2s[KP2];

    const int tid = threadIdx.x;
    const int tx = tid & 63;
    const int ty = tid >> 6;

    if (tid < KP2) {
        int k = tid * 2;
        float w0 = (k     < LOW) ? W2[k]     : 0.f;
        float w1 = (k + 1 < LOW) ? W2[k + 1] : 0.f;
        U32H2 p; p.h = h2{(_Float16)w0, (_Float16)w1};
        w2s[tid] = p.u;
    }

    const int srow = tid >> 3, sq = tid & 7;

    uint2 ga = *(const uint2*)&hy_h[(size_t)(i0 + srow) * KP2 + sq * 2];
    uint2 gb = *(const uint2*)&hx_h[(size_t)(j0 + srow) * KP2 + sq * 2];

    float acc[8] = {0,0,0,0,0,0,0,0};

    const int NC = KP2 / 16;              // 10 chunks of 16 h2 (32 k)
    for (int c = 0; c < NC; ++c) {
        __syncthreads();
        Hy[srow][sq * 2]     = ga.x;
        Hy[srow][sq * 2 + 1] = ga.y;
        Hx[srow][sq * 2]     = gb.x;
        Hx[srow][sq * 2 + 1] = gb.y;
        __syncthreads();
        if (c + 1 < NC) {
            ga = *(const uint2*)&hy_h[(size_t)(i0 + srow) * KP2 + (c + 1) * 16 + sq * 2];
            gb = *(const uint2*)&hx_h[(size_t)(j0 + srow) * KP2 + (c + 1) * 16 + sq * 2];
        }
        #pragma unroll
        for (int kk = 0; kk < 16; ++kk) {
            h2 b = u2h(Hx[tx][kk]);                   // stride-17: conflict-free
            h2 w = u2h(w2s[c * 16 + kk]);
            #pragma unroll
            for (int r = 0; r < 8; ++r) {
                h2 a = u2h(Hy[ty * 8 + r][kk]);       // broadcast
                h2 s = a + b;                         // v_pk_add_f16
                h2 z = __builtin_elementwise_max(s, h2{(_Float16)0.f, (_Float16)0.f});
                acc[r] = __builtin_amdgcn_fdot2(z, w, acc[r], false);
            }
        }
    }

    const float b2v = b2[0];
    #pragma unroll
    for (int r = 0; r < 8; ++r) {
        float sv = acc[r] + b2v;
        float sp = fmaxf(sv, 0.f) + __logf(1.f + __expf(-fabsf(sv)));
        T1[(size_t)(i0 + ty * 8 + r) * N_S + j0 + tx] = sp;
    }
}

// ---------------------------------------------------------------------------
// Kernel 3: per-row logsumexp + diagonal.  contrib[i] = T1[i][i] - lse_i
// ---------------------------------------------------------------------------
__device__ inline float waveReduceMax(float v) {
    #pragma unroll
    for (int o = 32; o > 0; o >>= 1) v = fmaxf(v, __shfl_down(v, o, 64));
    return v;
}
__device__ inline float waveReduceSum(float v) {
    #pragma unroll
    for (int o = 32; o > 0; o >>= 1) v += __shfl_down(v, o, 64);
    return v;
}

__global__ __launch_bounds__(256)
void row_reduce(const float* __restrict__ T1, float* __restrict__ contrib)
{
    const int i = blockIdx.x;
    const int tid = threadIdx.x;
    const float4 v = ((const float4*)(T1 + (size_t)i * N_S))[tid];

    __shared__ float sm[4];
    __shared__ float ss[4];
    const int wid = tid >> 6, lane = tid & 63;

    float m = fmaxf(fmaxf(v.x, v.y), fmaxf(v.z, v.w));
    m = waveReduceMax(m);
    if (lane == 0) sm[wid] = m;
    __syncthreads();
    const float M = fmaxf(fmaxf(sm[0], sm[1]), fmaxf(sm[2], sm[3]));

    float s = expf(v.x - M) + expf(v.y - M) + expf(v.z - M) + expf(v.w - M);
    s = waveReduceSum(s);
    if (lane == 0) ss[wid] = s;
    __syncthreads();

    if (tid == 0) {
        float lse = M + logf(ss[0] + ss[1] + ss[2] + ss[3]);
        contrib[i] = T1[(size_t)i * N_S + i] - lse;
    }
}

__global__ __launch_bounds__(256)
void finalize(const float* __restrict__ contrib, float* __restrict__ out)
{
    const int tid = threadIdx.x;
    float s = 0.f;
    for (int j = tid; j < N_S; j += 256) s += contrib[j];
    s = waveReduceSum(s);
    __shared__ float ss[4];
    const int wid = tid >> 6, lane = tid & 63;
    if (lane == 0) ss[wid] = s;
    __syncthreads();
    if (tid == 0)
        out[0] = (ss[0] + ss[1] + ss[2] + ss[3]) * (1.0f / N_S) - logf((float)N_S);
}

// ---------------------------------------------------------------------------
extern "C" void kernel_launch(void* const* d_in, const int* in_sizes, int n_in,
                              void* d_out, int out_size, void* d_ws, size_t ws_size,
                              hipStream_t stream)
{
    const float* x  = (const float*)d_in[0];
    const float* y  = (const float*)d_in[1];
    const float* W1 = (const float*)d_in[2];
    const float* b1 = (const float*)d_in[3];
    const float* W2 = (const float*)d_in[4];
    const float* b2 = (const float*)d_in[5];
    float* out = (float*)d_out;

    unsigned int* hx_h = (unsigned int*)d_ws;              // N_S * KP2 u32
    unsigned int* hy_h = hx_h + (size_t)N_S * KP2;         // N_S * KP2 u32
    float* T1      = (float*)(hy_h + (size_t)N_S * KP2);   // N_S * N_S f32
    float* contrib = T1 + (size_t)N_S * N_S;               // N_S

    dim3 g1(5, 16, 2);                    // ktiles(320/64), rowtiles, {x,y}
    gemm_h<<<g1, 512, 0, stream>>>(x, y, W1, b1, hx_h, hy_h);

    dim3 g2(16, 16);                      // j-tiles, i-tiles
    pair_kernel<<<g2, 512, 0, stream>>>(hx_h, hy_h, W2, b2, T1);

    row_reduce<<<N_S, 256, 0, stream>>>(T1, contrib);
    finalize<<<1, 256, 0, stream>>>(contrib, out);
}

// Round 5
// 48.096 us; speedup vs baseline: 3.1805x; 1.3958x over previous
//
#include <hip/hip_runtime.h>
#include <math.h>

#define N_S  1024
#define XD   768
#define LOW  300
#define KP   320     // f16 k-padding
#define KP2  160     // u32 (h2) per row

typedef _Float16 h2  __attribute__((ext_vector_type(2)));
typedef __fp16   g2  __attribute__((ext_vector_type(2)));
typedef _Float16 v8h __attribute__((ext_vector_type(8)));
typedef float    f4  __attribute__((ext_vector_type(4)));

union U32H2 { unsigned int u; h2 h; };
__device__ inline h2 u2h(unsigned int v){ U32H2 t; t.u = v; return t.h; }
union H8 { v8h v; h2 h[4]; };
__device__ inline h2 cvt2(float a, float b) {
    g2 t = __builtin_amdgcn_cvt_pkrtz(a, b);
    return __builtin_bit_cast(h2, t);
}

#define STRA 36     // As stride (f32), 144B: b128-aligned, conflict-free frag reads
#define STRB 67     // Bs stride (f32)

// ---------------------------------------------------------------------------
// Kernel 1: projections via MFMA f16 (fp32 acc).
//   which==0 : hx[j][k] = sum_m x[j,m]*W1[m,k]
//   which==1 : hy[i][k] = sum_m y[i,m]*W1[768+m,k] + b1[k]
// Block: 64(M) x 64(N=kcols) tile, 256 thr = 4 waves (2x2), K-step 32,
// double-buffered LDS (1 barrier/step). f32 staged; cvt_pkrtz at frag load.
// ---------------------------------------------------------------------------
__global__ __launch_bounds__(256)
void gemm_h(const float* __restrict__ x, const float* __restrict__ y,
            const float* __restrict__ W1, const float* __restrict__ b1g,
            _Float16* __restrict__ hx_h, _Float16* __restrict__ hy_h)
{
    const int which = blockIdx.z;
    const float* A = which ? y : x;
    const float* W = W1 + (size_t)which * XD * LOW;
    _Float16* out = which ? hy_h : hx_h;

    const int n0 = blockIdx.x * 64;     // kcol tile
    const int r0 = blockIdx.y * 64;     // sample-row tile

    __shared__ float As[2][64][STRA];
    __shared__ float Bs[2][32][STRB];

    const int tid = threadIdx.x;
    const int w = tid >> 6, l = tid & 63;
    const int wm = w >> 1, wn = w & 1;
    const int lr = l & 15, lg = l >> 4;      // frag row/col, k-group

    const int arow = tid >> 2, aq = tid & 3; // A staging
    const int bn = tid & 63, bk0 = tid >> 6; // B staging
    const bool bin = (n0 + bn) < LOW;

    f4 acc[2][2] = {};

    float4 av0, av1; float bw[8];
    av0 = *(const float4*)&A[(size_t)(r0 + arow) * XD + aq * 8];
    av1 = *(const float4*)&A[(size_t)(r0 + arow) * XD + aq * 8 + 4];
    #pragma unroll
    for (int s = 0; s < 8; ++s)
        bw[s] = bin ? W[(size_t)(bk0 + s * 4) * LOW + n0 + bn] : 0.f;

    const int NC = XD / 32;                  // 24
    for (int c = 0; c < NC; ++c) {
        const int buf = c & 1;
        *(float4*)&As[buf][arow][aq * 8]     = av0;
        *(float4*)&As[buf][arow][aq * 8 + 4] = av1;
        #pragma unroll
        for (int s = 0; s < 8; ++s)
            Bs[buf][bk0 + s * 4][bn] = bw[s];
        __syncthreads();
        if (c + 1 < NC) {
            const int kb = (c + 1) * 32;
            av0 = *(const float4*)&A[(size_t)(r0 + arow) * XD + kb + aq * 8];
            av1 = *(const float4*)&A[(size_t)(r0 + arow) * XD + kb + aq * 8 + 4];
            #pragma unroll
            for (int s = 0; s < 8; ++s)
                bw[s] = bin ? W[(size_t)(kb + bk0 + s * 4) * LOW + n0 + bn] : 0.f;
        }
        const int kloc = lg * 8;
        H8 af[2], bf[2];
        #pragma unroll
        for (int mt = 0; mt < 2; ++mt) {
            float4 t0 = *(const float4*)&As[buf][wm * 32 + mt * 16 + lr][kloc];
            float4 t1 = *(const float4*)&As[buf][wm * 32 + mt * 16 + lr][kloc + 4];
            af[mt].h[0] = cvt2(t0.x, t0.y);
            af[mt].h[1] = cvt2(t0.z, t0.w);
            af[mt].h[2] = cvt2(t1.x, t1.y);
            af[mt].h[3] = cvt2(t1.z, t1.w);
        }
        #pragma unroll
        for (int nt = 0; nt < 2; ++nt) {
            const int nn = wn * 32 + nt * 16 + lr;
            float e0 = Bs[buf][kloc + 0][nn], e1 = Bs[buf][kloc + 1][nn];
            float e2 = Bs[buf][kloc + 2][nn], e3 = Bs[buf][kloc + 3][nn];
            float e4 = Bs[buf][kloc + 4][nn], e5 = Bs[buf][kloc + 5][nn];
            float e6 = Bs[buf][kloc + 6][nn], e7 = Bs[buf][kloc + 7][nn];
            bf[nt].h[0] = cvt2(e0, e1);
            bf[nt].h[1] = cvt2(e2, e3);
            bf[nt].h[2] = cvt2(e4, e5);
            bf[nt].h[3] = cvt2(e6, e7);
        }
        #pragma unroll
        for (int mt = 0; mt < 2; ++mt)
            #pragma unroll
            for (int nt = 0; nt < 2; ++nt)
                acc[mt][nt] = __builtin_amdgcn_mfma_f32_16x16x32_f16(
                    af[mt].v, bf[nt].v, acc[mt][nt], 0, 0, 0);
    }

    // epilogue: D col = l&15, row = 4*(l>>4)+r
    #pragma unroll
    for (int nt = 0; nt < 2; ++nt) {
        const int col = n0 + wn * 32 + nt * 16 + lr;
        const float b1v = (which && col < LOW) ? b1g[col] : 0.f;
        #pragma unroll
        for (int mt = 0; mt < 2; ++mt) {
            #pragma unroll
            for (int r = 0; r < 4; ++r) {
                const int row = r0 + wm * 32 + mt * 16 + lg * 4 + r;
                out[(size_t)row * KP + col] = (_Float16)(acc[mt][nt][r] + b1v);
            }
        }
    }
}

// ---------------------------------------------------------------------------
// Kernel 2: pairwise critic, packed f16 VALU.
//   T1[i][j] = softplus( sum_k relu(hy[i,k]+hx[j,k]) * w2[k] + b2 )
// Tile 32(i) x 64(j), 256 thr; per-thread 4 i x 2 j. LDS laid out [kk][row]
// so inner loop = 1 uniform b128 + 1 b64 + 1 b32 per 24 VALU ops.
// 512 blocks -> 2 blocks/CU. Double-buffered, 1 barrier/chunk.
// ---------------------------------------------------------------------------
__global__ __launch_bounds__(256)
void pair_kernel(const unsigned int* __restrict__ hx_h, const unsigned int* __restrict__ hy_h,
                 const float* __restrict__ W2, const float* __restrict__ b2,
                 float* __restrict__ T1)
{
    const int j0 = blockIdx.x * 64;
    const int i0 = blockIdx.y * 32;

    __shared__ unsigned int Hy[2][16][36];   // [kk][i], stride 36 (144B, b128 ok)
    __shared__ unsigned int Hx[2][16][66];   // [kk][j], stride 66 (264B, b64 ok)
    __shared__ unsigned int w2s[KP2];

    const int tid = threadIdx.x;
    const int tx = tid & 31;                 // -> j pair 2*tx
    const int ty = tid >> 5;                 // -> i group 4*ty

    if (tid < KP2) {
        int k = tid * 2;
        float w0 = (k < LOW) ? W2[k] : 0.f;
        float w1 = (k + 1 < LOW) ? W2[k + 1] : 0.f;
        U32H2 p; p.h = h2{(_Float16)w0, (_Float16)w1};
        w2s[tid] = p.u;
    }

    const int yi = tid >> 3, yq = tid & 7;   // Hy staging: i, kk-pair
    const int xj = tid >> 2, xq = tid & 3;   // Hx staging: j, kk-quad

    uint2 ga  = *(const uint2*)&hy_h[(size_t)(i0 + yi) * KP2 + 2 * yq];
    uint2 gb0 = *(const uint2*)&hx_h[(size_t)(j0 + xj) * KP2 + 4 * xq];
    uint2 gb1 = *(const uint2*)&hx_h[(size_t)(j0 + xj) * KP2 + 4 * xq + 2];

    float acc[4][2] = {};
    const h2 hz = h2{(_Float16)0.f, (_Float16)0.f};

    const int NC = KP2 / 16;                 // 10
    for (int c = 0; c < NC; ++c) {
        const int buf = c & 1;
        Hy[buf][2 * yq][yi]     = ga.x;
        Hy[buf][2 * yq + 1][yi] = ga.y;
        Hx[buf][4 * xq][xj]     = gb0.x;
        Hx[buf][4 * xq + 1][xj] = gb0.y;
        Hx[buf][4 * xq + 2][xj] = gb1.x;
        Hx[buf][4 * xq + 3][xj] = gb1.y;
        __syncthreads();
        if (c + 1 < NC) {
            const int kb = (c + 1) * 16;
            ga  = *(const uint2*)&hy_h[(size_t)(i0 + yi) * KP2 + kb + 2 * yq];
            gb0 = *(const uint2*)&hx_h[(size_t)(j0 + xj) * KP2 + kb + 4 * xq];
            gb1 = *(const uint2*)&hx_h[(size_t)(j0 + xj) * KP2 + kb + 4 * xq + 2];
        }
        #pragma unroll
        for (int kk = 0; kk < 16; ++kk) {
            const uint4 ya = *(const uint4*)&Hy[buf][kk][ty * 4];
            const uint2 xb = *(const uint2*)&Hx[buf][kk][tx * 2];
            const h2 w  = u2h(w2s[c * 16 + kk]);
            const h2 x0 = u2h(xb.x), x1 = u2h(xb.y);
            const unsigned int yar[4] = {ya.x, ya.y, ya.z, ya.w};
            #pragma unroll
            for (int r = 0; r < 4; ++r) {
                const h2 a = u2h(yar[r]);
                h2 z0 = __builtin_elementwise_max(a + x0, hz);
                h2 z1 = __builtin_elementwise_max(a + x1, hz);
                acc[r][0] = __builtin_amdgcn_fdot2(z0, w, acc[r][0], false);
                acc[r][1] = __builtin_amdgcn_fdot2(z1, w, acc[r][1], false);
            }
        }
    }

    const float b2v = b2[0];
    #pragma unroll
    for (int r = 0; r < 4; ++r) {
        float s0 = acc[r][0] + b2v, s1 = acc[r][1] + b2v;
        float2 sp;
        sp.x = fmaxf(s0, 0.f) + __logf(1.f + __expf(-fabsf(s0)));
        sp.y = fmaxf(s1, 0.f) + __logf(1.f + __expf(-fabsf(s1)));
        *(float2*)&T1[(size_t)(i0 + ty * 4 + r) * N_S + j0 + tx * 2] = sp;
    }
}

// ---------------------------------------------------------------------------
// Kernel 3: one wave = one full row. Each lane reads 4 coalesced float4s
// (lane, lane+64, lane+128, lane+192) = 16 elems -> 64*16 = 1024 = full row.
// contrib[i] = T1[i][i] - logsumexp_j(T1[i][j])
// ---------------------------------------------------------------------------
__global__ __launch_bounds__(256)
void row_reduce(const float* __restrict__ T1, float* __restrict__ contrib)
{
    const int tid = threadIdx.x;
    const int wid = tid >> 6, lane = tid & 63;
    const int i = blockIdx.x * 4 + wid;
    const float4* row = (const float4*)(T1 + (size_t)i * N_S);

    float4 v[4];
    #pragma unroll
    for (int q = 0; q < 4; ++q) v[q] = row[lane + 64 * q];

    float m = -1e30f;
    #pragma unroll
    for (int q = 0; q < 4; ++q)
        m = fmaxf(m, fmaxf(fmaxf(v[q].x, v[q].y), fmaxf(v[q].z, v[q].w)));
    #pragma unroll
    for (int o = 32; o > 0; o >>= 1) m = fmaxf(m, __shfl_xor(m, o, 64));

    float s = 0.f;
    #pragma unroll
    for (int q = 0; q < 4; ++q)
        s += __expf(v[q].x - m) + __expf(v[q].y - m) +
             __expf(v[q].z - m) + __expf(v[q].w - m);
    #pragma unroll
    for (int o = 32; o > 0; o >>= 1) s += __shfl_xor(s, o, 64);

    if (lane == 0)
        contrib[i] = T1[(size_t)i * (N_S + 1)] - (m + __logf(s));
}

__global__ __launch_bounds__(256)
void finalize(const float* __restrict__ contrib, float* __restrict__ out)
{
    const int tid = threadIdx.x;
    float s = 0.f;
    for (int j = tid; j < N_S; j += 256) s += contrib[j];
    #pragma unroll
    for (int o = 32; o > 0; o >>= 1) s += __shfl_xor(s, o, 64);
    __shared__ float ss[4];
    const int wid = tid >> 6, lane = tid & 63;
    if (lane == 0) ss[wid] = s;
    __syncthreads();
    if (tid == 0)
        out[0] = (ss[0] + ss[1] + ss[2] + ss[3]) * (1.0f / N_S) - logf((float)N_S);
}

// ---------------------------------------------------------------------------
extern "C" void kernel_launch(void* const* d_in, const int* in_sizes, int n_in,
                              void* d_out, int out_size, void* d_ws, size_t ws_size,
                              hipStream_t stream)
{
    const float* x  = (const float*)d_in[0];
    const float* y  = (const float*)d_in[1];
    const float* W1 = (const float*)d_in[2];
    const float* b1 = (const float*)d_in[3];
    const float* W2 = (const float*)d_in[4];
    const float* b2 = (const float*)d_in[5];
    float* out = (float*)d_out;

    unsigned int* hx_h = (unsigned int*)d_ws;             // N_S*KP2 u32
    unsigned int* hy_h = hx_h + (size_t)N_S * KP2;
    float* T1      = (float*)(hy_h + (size_t)N_S * KP2);  // N_S*N_S f32
    float* contrib = T1 + (size_t)N_S * N_S;

    dim3 g1(5, 16, 2);
    gemm_h<<<g1, 256, 0, stream>>>(x, y, W1, b1,
                                   (_Float16*)hx_h, (_Float16*)hy_h);

    dim3 g2(16, 32);
    pair_kernel<<<g2, 256, 0, stream>>>(hx_h, hy_h, W2, b2, T1);

    row_reduce<<<N_S / 4, 256, 0, stream>>>(T1, contrib);
    finalize<<<1, 256, 0, stream>>>(contrib, out);
}

// Round 6
// 41.846 us; speedup vs baseline: 3.6555x; 1.1494x over previous
//
#include <hip/hip_runtime.h>
#include <math.h>

#define N_S 1024
#define XD  768
#define LOW 300
#define KP  320     // f16 k-padding
#define KP2 160     // u32 (h2) per row

typedef _Float16 h2  __attribute__((ext_vector_type(2)));
typedef __fp16   g2  __attribute__((ext_vector_type(2)));
typedef _Float16 v8h __attribute__((ext_vector_type(8)));
typedef float    f4  __attribute__((ext_vector_type(4)));

union U32H2 { unsigned int u; h2 h; };
__device__ inline h2 u2h(unsigned int v){ U32H2 t; t.u = v; return t.h; }
__device__ inline unsigned int pk(float a, float b){
    g2 t = __builtin_amdgcn_cvt_pkrtz(a, b);
    return __builtin_bit_cast(unsigned int, t);
}
union U4V8 { uint4 u; v8h v; };

#define STR 34   // u32 row stride (64 f16 + 2-u32 pad): frag b128 reads 2-way (free)

// ---------------------------------------------------------------------------
// Kernel 1: projections via MFMA f16, f16 staged directly in LDS.
//   which==0 : hx[j][k] = sum_m x[j,m]*W1[m,k]
//   which==1 : hy[i][k] = sum_m y[i,m]*W1[768+m,k] + b1[k]
// 64(M) x 64(N=kcol) tile, 512 thr = 8 waves (wn 4 x wm 2), K-step 64,
// double-buffered LDS, register prefetch, 1 barrier/step.
// ---------------------------------------------------------------------------
__global__ __launch_bounds__(512)
void gemm_h(const float* __restrict__ x, const float* __restrict__ y,
            const float* __restrict__ W1, const float* __restrict__ b1g,
            _Float16* __restrict__ hx_h, _Float16* __restrict__ hy_h)
{
    const int which = blockIdx.z;
    const float* A = which ? y : x;
    const float* W = W1 + (size_t)which * XD * LOW;
    _Float16* out = which ? hy_h : hx_h;

    const int n0 = blockIdx.x * 64;
    const int r0 = blockIdx.y * 64;

    __shared__ unsigned int As[2][64][STR];   // [row][k/2]
    __shared__ unsigned int Bs[2][64][STR];   // [ncol][k/2]

    const int tid = threadIdx.x;
    const int w = tid >> 6, l = tid & 63;
    const int wn = w >> 1, wm = w & 1;
    const int lr = l & 15, lg = l >> 4;

    const int arow = tid >> 3, aq = tid & 7;   // A staging: row, 8-m group
    const int bn = tid & 63, bms = tid >> 6;   // B staging: ncol, 8-m group
    const bool bin = (n0 + bn) < LOW;

    f4 acc[2] = {};

    float4 a0, a1; float bw[8];
    a0 = *(const float4*)&A[(size_t)(r0 + arow) * XD + aq * 8];
    a1 = *(const float4*)&A[(size_t)(r0 + arow) * XD + aq * 8 + 4];
    #pragma unroll
    for (int s = 0; s < 8; ++s)
        bw[s] = bin ? W[(size_t)(bms * 8 + s) * LOW + n0 + bn] : 0.f;

    const int NC = XD / 64;                    // 12
    for (int c = 0; c < NC; ++c) {
        const int buf = c & 1;
        {
            uint4 pa = { pk(a0.x,a0.y), pk(a0.z,a0.w), pk(a1.x,a1.y), pk(a1.z,a1.w) };
            *(uint4*)&As[buf][arow][aq * 4] = pa;
            uint4 pb = { pk(bw[0],bw[1]), pk(bw[2],bw[3]), pk(bw[4],bw[5]), pk(bw[6],bw[7]) };
            *(uint4*)&Bs[buf][bn][bms * 4] = pb;
        }
        __syncthreads();
        if (c + 1 < NC) {
            const int kb = (c + 1) * 64;
            a0 = *(const float4*)&A[(size_t)(r0 + arow) * XD + kb + aq * 8];
            a1 = *(const float4*)&A[(size_t)(r0 + arow) * XD + kb + aq * 8 + 4];
            #pragma unroll
            for (int s = 0; s < 8; ++s)
                bw[s] = bin ? W[(size_t)(kb + bms * 8 + s) * LOW + n0 + bn] : 0.f;
        }
        #pragma unroll
        for (int ks = 0; ks < 2; ++ks) {
            const int ko = ks * 16 + lg * 4;
            U4V8 bf; bf.u = *(const uint4*)&Bs[buf][wn * 16 + lr][ko];
            #pragma unroll
            for (int mt = 0; mt < 2; ++mt) {
                U4V8 af; af.u = *(const uint4*)&As[buf][wm * 32 + mt * 16 + lr][ko];
                acc[mt] = __builtin_amdgcn_mfma_f32_16x16x32_f16(af.v, bf.v, acc[mt], 0, 0, 0);
            }
        }
    }

    // D: col = l&15, row = 4*(l>>4)+r  (m89-verified)
    const int col = n0 + wn * 16 + lr;
    const float b1v = (which && col < LOW) ? b1g[col] : 0.f;
    #pragma unroll
    for (int mt = 0; mt < 2; ++mt)
        #pragma unroll
        for (int r = 0; r < 4; ++r) {
            const int row = r0 + wm * 32 + mt * 16 + lg * 4 + r;
            out[(size_t)row * KP + col] = (_Float16)(acc[mt][r] + b1v);
        }
}

// ---------------------------------------------------------------------------
// Kernel 2: pairwise critic + fused partial row-sum-of-exp.
//   sp[i][j] = softplus( sum_k relu(hy[i,k]+hx[j,k]) * w2[k] + b2 )
//   part[i][jb] = sum_{j in block jb} exp(sp[i][j]);  diag[i] = sp[i][i]
// sp is bounded (~<9), so direct exp-sum in f32 is safe (no max pass).
// Tile 32(i) x 64(j), 256 thr; per-thread 4 i x 2 j.
// ---------------------------------------------------------------------------
__global__ __launch_bounds__(256)
void pair_kernel(const unsigned int* __restrict__ hx_h, const unsigned int* __restrict__ hy_h,
                 const float* __restrict__ W2, const float* __restrict__ b2,
                 float* __restrict__ part, float* __restrict__ diag)
{
    const int j0 = blockIdx.x * 64;
    const int i0 = blockIdx.y * 32;
    const int jb = blockIdx.x;

    __shared__ unsigned int Hy[2][16][36];   // [kk][i]
    __shared__ unsigned int Hx[2][16][66];   // [kk][j]
    __shared__ unsigned int w2s[KP2];

    const int tid = threadIdx.x;
    const int tx = tid & 31;                 // j pair 2*tx
    const int ty = tid >> 5;                 // i group 4*ty

    if (tid < KP2) {
        int k = tid * 2;
        float w0 = (k < LOW) ? W2[k] : 0.f;
        float w1 = (k + 1 < LOW) ? W2[k + 1] : 0.f;
        U32H2 p; p.h = h2{(_Float16)w0, (_Float16)w1};
        w2s[tid] = p.u;
    }

    const int yi = tid >> 3, yq = tid & 7;   // Hy staging
    const int xj = tid >> 2, xq = tid & 3;   // Hx staging

    uint2 ga  = *(const uint2*)&hy_h[(size_t)(i0 + yi) * KP2 + 2 * yq];
    uint2 gb0 = *(const uint2*)&hx_h[(size_t)(j0 + xj) * KP2 + 4 * xq];
    uint2 gb1 = *(const uint2*)&hx_h[(size_t)(j0 + xj) * KP2 + 4 * xq + 2];

    float acc[4][2] = {};
    const h2 hz = h2{(_Float16)0.f, (_Float16)0.f};

    const int NC = KP2 / 16;                 // 10
    for (int c = 0; c < NC; ++c) {
        const int buf = c & 1;
        Hy[buf][2 * yq][yi]     = ga.x;
        Hy[buf][2 * yq + 1][yi] = ga.y;
        Hx[buf][4 * xq][xj]     = gb0.x;
        Hx[buf][4 * xq + 1][xj] = gb0.y;
        Hx[buf][4 * xq + 2][xj] = gb1.x;
        Hx[buf][4 * xq + 3][xj] = gb1.y;
        __syncthreads();
        if (c + 1 < NC) {
            const int kb = (c + 1) * 16;
            ga  = *(const uint2*)&hy_h[(size_t)(i0 + yi) * KP2 + kb + 2 * yq];
            gb0 = *(const uint2*)&hx_h[(size_t)(j0 + xj) * KP2 + kb + 4 * xq];
            gb1 = *(const uint2*)&hx_h[(size_t)(j0 + xj) * KP2 + kb + 4 * xq + 2];
        }
        #pragma unroll
        for (int kk = 0; kk < 16; ++kk) {
            const uint4 ya = *(const uint4*)&Hy[buf][kk][ty * 4];
            const uint2 xb = *(const uint2*)&Hx[buf][kk][tx * 2];
            const h2 w  = u2h(w2s[c * 16 + kk]);
            const h2 x0 = u2h(xb.x), x1 = u2h(xb.y);
            const unsigned int yar[4] = {ya.x, ya.y, ya.z, ya.w};
            #pragma unroll
            for (int r = 0; r < 4; ++r) {
                const h2 a = u2h(yar[r]);
                h2 z0 = __builtin_elementwise_max(a + x0, hz);
                h2 z1 = __builtin_elementwise_max(a + x1, hz);
                acc[r][0] = __builtin_amdgcn_fdot2(z0, w, acc[r][0], false);
                acc[r][1] = __builtin_amdgcn_fdot2(z1, w, acc[r][1], false);
            }
        }
    }

    const float b2v = b2[0];
    #pragma unroll
    for (int r = 0; r < 4; ++r) {
        const int row = i0 + ty * 4 + r;
        float s0 = acc[r][0] + b2v, s1 = acc[r][1] + b2v;
        float sp0 = fmaxf(s0, 0.f) + __logf(1.f + __expf(-fabsf(s0)));
        float sp1 = fmaxf(s1, 0.f) + __logf(1.f + __expf(-fabsf(s1)));
        const int c0 = j0 + tx * 2;
        if (c0 == row)     diag[row] = sp0;
        if (c0 + 1 == row) diag[row] = sp1;
        float es = __expf(sp0) + __expf(sp1);
        // reduce over the 32 tx lanes (same half-wave)
        #pragma unroll
        for (int o = 1; o <= 16; o <<= 1) es += __shfl_xor(es, o, 64);
        if ((tid & 31) == 0) part[(size_t)row * 16 + jb] = es;
    }
}

// ---------------------------------------------------------------------------
// Kernel 3: per-row lse from 16 partials + final mean. One 1024-thr block.
// ---------------------------------------------------------------------------
__global__ __launch_bounds__(1024)
void lse_final(const float* __restrict__ part, const float* __restrict__ diag,
               float* __restrict__ out)
{
    const int i = threadIdx.x;
    const float4* p = (const float4*)(part + (size_t)i * 16);
    float s = 0.f;
    #pragma unroll
    for (int q = 0; q < 4; ++q) {
        float4 v = p[q];
        s += (v.x + v.y) + (v.z + v.w);
    }
    float c = diag[i] - __logf(s);

    #pragma unroll
    for (int o = 32; o > 0; o >>= 1) c += __shfl_xor(c, o, 64);
    __shared__ float ss[16];
    const int wid = i >> 6, lane = i & 63;
    if (lane == 0) ss[wid] = c;
    __syncthreads();
    if (i == 0) {
        float t = 0.f;
        #pragma unroll
        for (int q = 0; q < 16; ++q) t += ss[q];
        out[0] = t * (1.0f / N_S) - logf((float)N_S);
    }
}

// ---------------------------------------------------------------------------
extern "C" void kernel_launch(void* const* d_in, const int* in_sizes, int n_in,
                              void* d_out, int out_size, void* d_ws, size_t ws_size,
                              hipStream_t stream)
{
    const float* x  = (const float*)d_in[0];
    const float* y  = (const float*)d_in[1];
    const float* W1 = (const float*)d_in[2];
    const float* b1 = (const float*)d_in[3];
    const float* W2 = (const float*)d_in[4];
    const float* b2 = (const float*)d_in[5];
    float* out = (float*)d_out;

    unsigned int* hx_h = (unsigned int*)d_ws;             // N_S*KP2 u32
    unsigned int* hy_h = hx_h + (size_t)N_S * KP2;        // N_S*KP2 u32
    float* part = (float*)(hy_h + (size_t)N_S * KP2);     // N_S*16 f32
    float* diag = part + (size_t)N_S * 16;                // N_S f32

    dim3 g1(5, 16, 2);                    // ktiles(320/64), rowtiles, {x,y}
    gemm_h<<<g1, 512, 0, stream>>>(x, y, W1, b1,
                                   (_Float16*)hx_h, (_Float16*)hy_h);

    dim3 g2(16, 32);                      // j-tiles, i-tiles
    pair_kernel<<<g2, 256, 0, stream>>>(hx_h, hy_h, W2, b2, part, diag);

    lse_final<<<1, 1024, 0, stream>>>(part, diag, out);
}